// Round 8
// baseline (767.142 us; speedup 1.0000x reference)
//
#include <hip/hip_runtime.h>
#include <cstdint>
#include <cstddef>

// ---------------- constants ----------------
#define DIMC   384
#define NHEAD  12
#define HDIM   32
#define WSZ    7
#define NTOK   49          // 7*7
#define HW     56
#define SPIMG  3136        // 56*56
#define M_TOT  50176       // 16*3136 token rows
#define MHALF  25088       // M_TOT/2 (MLP processed in two halves to fit ws)
#define HIDDEN 1536
#define QKVN   1152        // qkv output row width

typedef __attribute__((ext_vector_type(8))) short short8;
typedef __attribute__((ext_vector_type(4))) float f32x4;

__device__ __forceinline__ short f2bf(float f) {
  uint32_t u = __builtin_bit_cast(uint32_t, f);
  u = (u + 0x7fffu + ((u >> 16) & 1u)) >> 16;   // RNE
  return (short)u;
}
__device__ __forceinline__ float bf2f(short s) {
  uint32_t u = ((uint32_t)(uint16_t)s) << 16;
  return __builtin_bit_cast(float, u);
}

__device__ __forceinline__ void async16(const short* g, short* l) {
  __builtin_amdgcn_global_load_lds(
      (const __attribute__((address_space(1))) uint32_t*)g,
      (__attribute__((address_space(3))) uint32_t*)l, 16, 0, 0);
}

// ---------------- all weight casts+transposes in ONE kernel ----------------
__global__ void wt_all_kernel(const float* __restrict__ qkv_w, const float* __restrict__ proj_w,
                              const float* __restrict__ fc1_w, const float* __restrict__ fc2_w,
                              short* __restrict__ qkvT, short* __restrict__ projT,
                              short* __restrict__ fc1T, short* __restrict__ fc2T) {
  int idx = blockIdx.x * 256 + threadIdx.x;
  const float* src; short* dst; int K, N;
  if (idx < 442368)       { src = qkv_w;  dst = qkvT;  K = 384;  N = 1152; }
  else if (idx < 589824)  { idx -= 442368; src = proj_w; dst = projT; K = 384;  N = 384; }
  else if (idx < 1179648) { idx -= 589824; src = fc1_w;  dst = fc1T;  K = 384;  N = 1536; }
  else if (idx < 1769472) { idx -= 1179648; src = fc2_w; dst = fc2T;  K = 1536; N = 384; }
  else return;
  int k = idx / N, n = idx - k * N;
  dst[(size_t)n * K + k] = f2bf(src[idx]);
}

// ---------------- LN1 + roll(-3,-3) + window partition; xl residual in WINDOW-TOKEN order ----------------
__global__ __launch_bounds__(256) void ln1_win_kernel(const float* __restrict__ x,
                                                      const float* __restrict__ w,
                                                      const float* __restrict__ b,
                                                      float* __restrict__ xl,
                                                      short* __restrict__ win) {
  __shared__ float tile[32][385];
  int bid = blockIdx.x;                    // 16 * 98
  int img = bid / 98;
  int s0  = (bid - img * 98) * 32;
  const float* xp = x + (size_t)img * DIMC * SPIMG;
  int tid = threadIdx.x;
  #pragma unroll 4
  for (int it = 0; it < 48; ++it) {
    int idx = it * 256 + tid;
    int s = idx & 31, c = idx >> 5;
    tile[s][c] = xp[(size_t)c * SPIMG + s0 + s];
  }
  __syncthreads();
  int wave = tid >> 6, lane = tid & 63;
  for (int i = 0; i < 8; ++i) {
    int sl = wave * 8 + i;
    int s  = s0 + sl;
    float v[6]; float sum = 0.f, ss = 0.f;
    #pragma unroll
    for (int j = 0; j < 6; ++j) { v[j] = tile[sl][j * 64 + lane]; sum += v[j]; ss += v[j] * v[j]; }
    #pragma unroll
    for (int o = 32; o; o >>= 1) { sum += __shfl_xor(sum, o); ss += __shfl_xor(ss, o); }
    float mu   = sum * (1.f / 384.f);
    float var  = ss * (1.f / 384.f) - mu * mu;
    float rstd = rsqrtf(var + 1e-5f);
    int h = s / HW, wc = s - h * HW;
    int ir = h - 3;  if (ir < 0) ir += HW;
    int jr = wc - 3; if (jr < 0) jr += HW;
    int widx = img * 64 + (ir / WSZ) * 8 + (jr / WSZ);
    int tok  = (ir % WSZ) * WSZ + (jr % WSZ);
    size_t wrow = (size_t)(widx * NTOK + tok);
    float* xlr = xl + wrow * DIMC;          // residual in window order
    short* wr  = win + wrow * DIMC;
    #pragma unroll
    for (int j = 0; j < 6; ++j) {
      int c = j * 64 + lane;
      xlr[c] = v[j];
      wr[c]  = f2bf((v[j] - mu) * rstd * w[c] + b[c]);
    }
  }
}

// ---------------- GEMM core: 128x128 tile, BK=64, 4 waves, 16x16x32 bf16 MFMA ----------------
__device__ __forceinline__ void gemm_core(const short* __restrict__ A, int lda,
                                          const short* __restrict__ Bt, int ldb, int K,
                                          int m0, int n0, short* sA, short* sB,
                                          f32x4 acc[4][4]) {
  const int tid = threadIdx.x;
  const int wave = tid >> 6, lane = tid & 63;
  const int wm = (wave >> 1) << 6, wn = (wave & 1) << 6;
  const int lr = lane & 15, lk = lane >> 4;
  #pragma unroll
  for (int i = 0; i < 4; ++i)
    #pragma unroll
    for (int j = 0; j < 4; ++j)
      #pragma unroll
      for (int q = 0; q < 4; ++q) acc[i][j][q] = 0.f;

  for (int kt = 0; kt < K; kt += 64) {
    #pragma unroll
    for (int r = 0; r < 4; ++r) {
      int flat = r * 256 + tid;
      int row  = flat >> 3;
      int pcol = flat & 7;
      int lcol = pcol ^ (row & 7);            // inverse-swizzled global source
      async16(A  + (size_t)(m0 + row) * lda + kt + lcol * 8, sA + flat * 8);
      async16(Bt + (size_t)(n0 + row) * ldb + kt + lcol * 8, sB + flat * 8);
    }
    __syncthreads();
    #pragma unroll
    for (int kk = 0; kk < 2; ++kk) {
      short8 a[4], bfr[4];
      #pragma unroll
      for (int i = 0; i < 4; ++i) {
        int ra = wm + i * 16 + lr;
        int sa_ = (kk * 4 + lk) ^ (ra & 7);   // swizzled read
        a[i] = *(const short8*)(sA + ra * 64 + sa_ * 8);
        int rb = wn + i * 16 + lr;
        int sb_ = (kk * 4 + lk) ^ (rb & 7);
        bfr[i] = *(const short8*)(sB + rb * 64 + sb_ * 8);
      }
      #pragma unroll
      for (int i = 0; i < 4; ++i)
        #pragma unroll
        for (int j = 0; j < 4; ++j)
          acc[i][j] = __builtin_amdgcn_mfma_f32_16x16x32_bf16(a[i], bfr[j], acc[i][j], 0, 0, 0);
    }
    __syncthreads();
  }
}

// D-frag mapping (m89-verified): col = lane&15, row = (lane>>4)*4 + reg
#define EPI_PROLOGUE \
  const int tid = threadIdx.x; const int wave = tid >> 6, lane = tid & 63; \
  const int wm = (wave >> 1) << 6, wn = (wave & 1) << 6; \
  const int lr = lane & 15, lk = lane >> 4;

// ---------------- qkv GEMM: plain row-major [M][1152] output (mt-major order) ----------------
__global__ __launch_bounds__(256) void gemm_qkv(const short* __restrict__ A, const short* __restrict__ Bt,
                                                const float* __restrict__ bias, short* __restrict__ qkvr) {
  __shared__ __align__(16) short sA[8192], sB[8192];
  int mt = blockIdx.x / 9, nt = blockIdx.x - mt * 9;   // mt-major: 9 consecutive blocks share A-tile
  int m0 = mt << 7, n0 = nt << 7;
  f32x4 acc[4][4];
  gemm_core(A, 384, Bt, 384, 384, m0, n0, sA, sB, acc);
  EPI_PROLOGUE
  #pragma unroll
  for (int i = 0; i < 4; ++i)
    #pragma unroll
    for (int j = 0; j < 4; ++j)
      #pragma unroll
      for (int rg = 0; rg < 4; ++rg) {
        int row = m0 + wm + i * 16 + lk * 4 + rg;
        int col = n0 + wn + j * 16 + lr;
        qkvr[(size_t)row * QKVN + col] = f2bf(acc[i][j][rg] + bias[col]);
      }
}

// ---------------- MFMA attention: one block per (window,head); gathers from row-major qkv ----------------
#define QSTR 40   // Q/K/Vr LDS row stride (shorts): 80B, 16B-aligned
#define VSTR 72   // Vt/E LDS row stride (shorts): 144B, 16B-aligned
__global__ __launch_bounds__(256) void attn_kernel(const short* __restrict__ qkvr,
                                                   short* __restrict__ attn_out) {
  __shared__ __align__(16) short sQ[64 * QSTR];   // rows 49..63 stale: isolated to discarded D rows
  __shared__ __align__(16) short sK[64 * QSTR];   // rows 49..63 stale: masked before max
  __shared__ __align__(16) short sVr[NTOK * QSTR];// V row-major temp
  __shared__ __align__(16) short sVt[32 * VSTR];  // [d][tok]; cols 49..63 zeroed
  __shared__ __align__(16) short sE[64 * VSTR];   // unnormalized exp, bf16
  int bx = blockIdx.x;                       // widx*12 + hd
  int widx = bx / 12, hd = bx - widx * 12;
  int tid = threadIdx.x;
  const int w = tid >> 6, lane = tid & 63;
  const int lr = lane & 15, lk = lane >> 4;
  const short* base = qkvr + (size_t)widx * NTOK * QKVN + hd * HDIM;
  for (int i = tid; i < 196; i += 256) {     // 49 rows x 4 chunks of 16B
    int tok = i >> 2, p = (i & 3) << 3;
    const short* rp = base + (size_t)tok * QKVN + p;
    *(short8*)(sQ  + tok * QSTR + p) = *(const short8*)(rp);
    *(short8*)(sK  + tok * QSTR + p) = *(const short8*)(rp + 384);
    *(short8*)(sVr + tok * QSTR + p) = *(const short8*)(rp + 768);
  }
  __syncthreads();
  for (int e = tid; e < 2048; e += 256) {    // V transpose + pad-zero: sVt[d][tok]
    int d = e >> 6, c = e & 63;
    sVt[d * VSTR + c] = (c < NTOK) ? sVr[c * QSTR + d] : (short)0;
  }
  // ---- QK^T ----
  short8 aq = *(const short8*)(sQ + (16 * w + lr) * QSTR + lk * 8);
  f32x4 zero = {0.f, 0.f, 0.f, 0.f};
  f32x4 s4[4];
  #pragma unroll
  for (int j = 0; j < 4; ++j) {
    short8 bk = *(const short8*)(sK + (16 * j + lr) * QSTR + lk * 8);
    s4[j] = __builtin_amdgcn_mfma_f32_16x16x32_bf16(aq, bk, zero, 0, 0, 0);
  }
  // ---- softmax (rows (lane>>4)*4+rg of tile w; cols 16j+lr) ----
  float rinv[4];
  #pragma unroll
  for (int rg = 0; rg < 4; ++rg) {
    float v[4];
    #pragma unroll
    for (int j = 0; j < 4; ++j)
      v[j] = (16 * j + lr < NTOK) ? s4[j][rg] * 0.17677669529663687f : -3.0e38f;
    float m = fmaxf(fmaxf(v[0], v[1]), fmaxf(v[2], v[3]));
    #pragma unroll
    for (int o = 1; o < 16; o <<= 1) m = fmaxf(m, __shfl_xor(m, o));
    float e0 = __expf(v[0] - m), e1 = __expf(v[1] - m);
    float e2 = __expf(v[2] - m), e3 = __expf(v[3] - m);
    float sum = (e0 + e1) + (e2 + e3);
    #pragma unroll
    for (int o = 1; o < 16; o <<= 1) sum += __shfl_xor(sum, o);
    rinv[rg] = 1.f / sum;
    int erow = 16 * w + lk * 4 + rg;
    sE[erow * VSTR + lr]      = f2bf(e0);
    sE[erow * VSTR + 16 + lr] = f2bf(e1);
    sE[erow * VSTR + 32 + lr] = f2bf(e2);
    sE[erow * VSTR + 48 + lr] = f2bf(e3);
  }
  __syncthreads();                           // orders V-transpose + E writes before PV
  // ---- PV ----
  f32x4 o4[2] = {{0.f,0.f,0.f,0.f},{0.f,0.f,0.f,0.f}};
  #pragma unroll
  for (int ks = 0; ks < 2; ++ks) {
    short8 ae = *(const short8*)(sE + (16 * w + lr) * VSTR + ks * 32 + lk * 8);
    #pragma unroll
    for (int dt = 0; dt < 2; ++dt) {
      short8 bv = *(const short8*)(sVt + (16 * dt + lr) * VSTR + ks * 32 + lk * 8);
      o4[dt] = __builtin_amdgcn_mfma_f32_16x16x32_bf16(ae, bv, o4[dt], 0, 0, 0);
    }
  }
  #pragma unroll
  for (int rg = 0; rg < 4; ++rg) {
    int row = 16 * w + lk * 4 + rg;
    if (row < NTOK) {
      size_t rowbase = ((size_t)widx * NTOK + row) * DIMC + hd * HDIM;
      attn_out[rowbase + lr]      = f2bf(o4[0][rg] * rinv[rg]);
      attn_out[rowbase + 16 + lr] = f2bf(o4[1][rg] * rinv[rg]);
    }
  }
}

// ---------------- proj GEMM + LINEAR residual add into xl (window order) ----------------
__global__ __launch_bounds__(256) void gemm_proj(const short* __restrict__ A, const short* __restrict__ Bt,
                                                 const float* __restrict__ bias, float* __restrict__ xl) {
  __shared__ __align__(16) short sA[8192], sB[8192];
  int mt = blockIdx.x / 3, nt = blockIdx.x - mt * 3;
  int m0 = mt << 7, n0 = nt << 7;
  f32x4 acc[4][4];
  gemm_core(A, 384, Bt, 384, 384, m0, n0, sA, sB, acc);
  EPI_PROLOGUE
  #pragma unroll
  for (int i = 0; i < 4; ++i)
    #pragma unroll
    for (int j = 0; j < 4; ++j)
      #pragma unroll
      for (int rg = 0; rg < 4; ++rg) {
        int row = m0 + wm + i * 16 + lk * 4 + rg;
        int col = n0 + wn + j * 16 + lr;
        float* p = xl + (size_t)row * DIMC + col;
        *p = *p + acc[i][j][rg] + bias[col];
      }
}

// ---------------- LN2: xl f32 (window order) -> h2 bf16 ----------------
__global__ __launch_bounds__(256) void ln2_kernel(const float* __restrict__ xl, const float* __restrict__ w,
                                                  const float* __restrict__ b, short* __restrict__ h2) {
  int t = blockIdx.x * 4 + (threadIdx.x >> 6);
  int lane = threadIdx.x & 63;
  const float* row = xl + (size_t)t * DIMC;
  float v[6]; float sum = 0.f, ss = 0.f;
  #pragma unroll
  for (int j = 0; j < 3; ++j) {
    float2 p2 = *(const float2*)(row + j * 128 + lane * 2);
    v[2 * j] = p2.x; v[2 * j + 1] = p2.y;
    sum += p2.x + p2.y; ss += p2.x * p2.x + p2.y * p2.y;
  }
  #pragma unroll
  for (int o = 32; o; o >>= 1) { sum += __shfl_xor(sum, o); ss += __shfl_xor(ss, o); }
  float mu = sum * (1.f / 384.f);
  float var = ss * (1.f / 384.f) - mu * mu;
  float rstd = rsqrtf(var + 1e-5f);
  short* orow = h2 + (size_t)t * DIMC;
  #pragma unroll
  for (int j = 0; j < 3; ++j) {
    int c = j * 128 + lane * 2;
    short2 o2;
    o2.x = f2bf((v[2 * j] - mu) * rstd * w[c] + b[c]);
    o2.y = f2bf((v[2 * j + 1] - mu) * rstd * w[c + 1] + b[c + 1]);
    *(short2*)(orow + c) = o2;
  }
}

// ---------------- fc1 GEMM + exact GELU -> h3half ----------------
__global__ __launch_bounds__(256) void gemm_fc1(const short* __restrict__ A, const short* __restrict__ Bt,
                                                const float* __restrict__ bias, short* __restrict__ h3,
                                                int mbase) {
  __shared__ __align__(16) short sA[8192], sB[8192];
  int mt = blockIdx.x / 12, nt = blockIdx.x - mt * 12;   // mt-major
  int m0 = mbase + (mt << 7), n0 = nt << 7;
  f32x4 acc[4][4];
  gemm_core(A, 384, Bt, 384, 384, m0, n0, sA, sB, acc);
  EPI_PROLOGUE
  #pragma unroll
  for (int i = 0; i < 4; ++i)
    #pragma unroll
    for (int j = 0; j < 4; ++j)
      #pragma unroll
      for (int rg = 0; rg < 4; ++rg) {
        int row = m0 + wm + i * 16 + lk * 4 + rg;
        int col = n0 + wn + j * 16 + lr;
        float v = acc[i][j][rg] + bias[col];
        float g = 0.5f * v * (1.f + erff(v * 0.70710678118654752f));
        h3[(size_t)(row - mbase) * HIDDEN + col] = f2bf(g);
      }
}

// ---------------- fc2 GEMM + residual + un-window/un-roll NCHW store ----------------
__global__ __launch_bounds__(256) void gemm_fc2(const short* __restrict__ A, const short* __restrict__ Bt,
                                                const float* __restrict__ bias, const float* __restrict__ xl,
                                                float* __restrict__ out, int mbase) {
  __shared__ __align__(16) short sA[8192], sB[8192];
  int mt = blockIdx.x / 3, nt = blockIdx.x - mt * 3;     // mt-major
  int m0l = mt << 7, n0 = nt << 7;
  f32x4 acc[4][4];
  gemm_core(A, HIDDEN, Bt, HIDDEN, HIDDEN, m0l, n0, sA, sB, acc);
  EPI_PROLOGUE
  #pragma unroll
  for (int i = 0; i < 4; ++i)
    #pragma unroll
    for (int j = 0; j < 4; ++j)
      #pragma unroll
      for (int rg = 0; rg < 4; ++rg) {
        int row = mbase + m0l + wm + i * 16 + lk * 4 + rg;   // window-token row
        int col = n0 + wn + j * 16 + lr;
        float v = acc[i][j][rg] + bias[col] + xl[(size_t)row * DIMC + col];
        int widx = row / 49, tok = row - widx * 49;
        int bimg = widx >> 6, wrem = widx & 63;
        int wi = wrem >> 3, wj = wrem & 7;
        int ti = tok / 7, tj = tok - ti * 7;
        int hh = wi * 7 + ti + 3; if (hh >= HW) hh -= HW;    // roll back (+3,+3)
        int ww = wj * 7 + tj + 3; if (ww >= HW) ww -= HW;
        out[((size_t)bimg * DIMC + col) * SPIMG + hh * HW + ww] = v;
      }
}

// ---------------- workspace layout (bytes), total 246,546,432 ----------------
#define OFF_XL    0u                // 50176*384*4  = 77,070,336   f32 residual (window order)
#define OFF_WIN   77070336u         // 50176*384*2  = 38,535,168   bf16 LN1-out / attn_out / h2
#define OFF_QKV   115605504u        // region 127,401,984: qkv rows 115.6MB / h3half 77.1MB
#define OFF_QKVT  243007488u        // 1152*384*2
#define OFF_PROJT 243892224u        // 384*384*2
#define OFF_FC1T  244187136u        // 1536*384*2
#define OFF_FC2T  245366784u        // 384*1536*2   (end = 246,546,432)
#define WS_NEEDED 246546432u

extern "C" void kernel_launch(void* const* d_in, const int* in_sizes, int n_in,
                              void* d_out, int out_size, void* d_ws, size_t ws_size,
                              hipStream_t stream) {
  if (ws_size < (size_t)WS_NEEDED) return;   // graceful diagnostic fail (constant per-call)

  const float* x      = (const float*)d_in[0];
  const float* n1w    = (const float*)d_in[1];
  const float* n1b    = (const float*)d_in[2];
  const float* qkv_w  = (const float*)d_in[3];
  const float* qkv_b  = (const float*)d_in[4];
  const float* proj_w = (const float*)d_in[5];
  const float* proj_b = (const float*)d_in[6];
  const float* n2w    = (const float*)d_in[7];
  const float* n2b    = (const float*)d_in[8];
  const float* fc1_w  = (const float*)d_in[9];
  const float* fc1_b  = (const float*)d_in[10];
  const float* fc2_w  = (const float*)d_in[11];
  const float* fc2_b  = (const float*)d_in[12];
  float* out = (float*)d_out;

  char* ws = (char*)d_ws;
  float* xl    = (float*)(ws + OFF_XL);
  short* win   = (short*)(ws + OFF_WIN);    // LN1 token rows; reused: attn_out, then h2
  short* qkvr  = (short*)(ws + OFF_QKV);    // qkv row-major; reused: h3half
  short* h3    = (short*)(ws + OFF_QKV);    // alias (qkv dead by fc1 time)
  short* qkvT  = (short*)(ws + OFF_QKVT);
  short* projT = (short*)(ws + OFF_PROJT);
  short* fc1T  = (short*)(ws + OFF_FC1T);
  short* fc2T  = (short*)(ws + OFF_FC2T);

  wt_all_kernel<<<(1769472 + 255) / 256, 256, 0, stream>>>(qkv_w, proj_w, fc1_w, fc2_w,
                                                           qkvT, projT, fc1T, fc2T);
  ln1_win_kernel<<<16 * 98, 256, 0, stream>>>(x, n1w, n1b, xl, win);
  gemm_qkv<<<392 * 9, 256, 0, stream>>>(win, qkvT, qkv_b, qkvr);
  attn_kernel<<<1024 * 12, 256, 0, stream>>>(qkvr, win);          // win := attn_out
  gemm_proj<<<392 * 3, 256, 0, stream>>>(win, projT, proj_b, xl);
  ln2_kernel<<<12544, 256, 0, stream>>>(xl, n2w, n2b, win);       // win := h2
  gemm_fc1<<<196 * 12, 256, 0, stream>>>(win, fc1T, fc1_b, h3, 0);
  gemm_fc2<<<196 * 3,  256, 0, stream>>>(h3, fc2T, fc2_b, xl, out, 0);
  gemm_fc1<<<196 * 12, 256, 0, stream>>>(win, fc1T, fc1_b, h3, MHALF);
  gemm_fc2<<<196 * 3,  256, 0, stream>>>(h3, fc2T, fc2_b, xl, out, MHALF);

  (void)in_sizes; (void)n_in; (void)out_size; (void)ws_size;
}

// Round 11
// 688.067 us; speedup vs baseline: 1.1149x; 1.1149x over previous
//
#include <hip/hip_runtime.h>
#include <cstdint>
#include <cstddef>

// ---------------- constants ----------------
#define DIMC   384
#define NHEAD  12
#define HDIM   32
#define WSZ    7
#define NTOK   49          // 7*7
#define HW     56
#define SPIMG  3136        // 56*56
#define M_TOT  50176       // 16*3136 token rows
#define MHALF  25088       // M_TOT/2 = 8 images exactly
#define HIDDEN 1536
#define QKVN   1152        // qkv output row width

typedef __attribute__((ext_vector_type(8))) short short8;
typedef __attribute__((ext_vector_type(4))) float f32x4;

__device__ __forceinline__ short f2bf(float f) {
  uint32_t u = __builtin_bit_cast(uint32_t, f);
  u = (u + 0x7fffu + ((u >> 16) & 1u)) >> 16;   // RNE
  return (short)u;
}
__device__ __forceinline__ float bf2f(short s) {
  uint32_t u = ((uint32_t)(uint16_t)s) << 16;
  return __builtin_bit_cast(float, u);
}

__device__ __forceinline__ void async16(const short* g, short* l) {
  __builtin_amdgcn_global_load_lds(
      (const __attribute__((address_space(1))) uint32_t*)g,
      (__attribute__((address_space(3))) uint32_t*)l, 16, 0, 0);
}

// ---------------- all weight casts+transposes in ONE kernel ----------------
__global__ void wt_all_kernel(const float* __restrict__ qkv_w, const float* __restrict__ proj_w,
                              const float* __restrict__ fc1_w, const float* __restrict__ fc2_w,
                              short* __restrict__ qkvT, short* __restrict__ projT,
                              short* __restrict__ fc1T, short* __restrict__ fc2T) {
  int idx = blockIdx.x * 256 + threadIdx.x;
  const float* src; short* dst; int K, N;
  if (idx < 442368)       { src = qkv_w;  dst = qkvT;  K = 384;  N = 1152; }
  else if (idx < 589824)  { idx -= 442368; src = proj_w; dst = projT; K = 384;  N = 384; }
  else if (idx < 1179648) { idx -= 589824; src = fc1_w;  dst = fc1T;  K = 384;  N = 1536; }
  else if (idx < 1769472) { idx -= 1179648; src = fc2_w; dst = fc2T;  K = 1536; N = 384; }
  else return;
  int k = idx / N, n = idx - k * N;
  dst[(size_t)n * K + k] = f2bf(src[idx]);
}

// ---------------- LN1 + roll(-3,-3) + window partition; xl residual in WINDOW-TOKEN order ----------------
__global__ __launch_bounds__(256) void ln1_win_kernel(const float* __restrict__ x,
                                                      const float* __restrict__ w,
                                                      const float* __restrict__ b,
                                                      float* __restrict__ xl,
                                                      short* __restrict__ win) {
  __shared__ float tile[32][385];
  int bid = blockIdx.x;                    // 16 * 98
  int img = bid / 98;
  int s0  = (bid - img * 98) * 32;
  const float* xp = x + (size_t)img * DIMC * SPIMG;
  int tid = threadIdx.x;
  #pragma unroll 4
  for (int it = 0; it < 48; ++it) {
    int idx = it * 256 + tid;
    int s = idx & 31, c = idx >> 5;
    tile[s][c] = xp[(size_t)c * SPIMG + s0 + s];
  }
  __syncthreads();
  int wave = tid >> 6, lane = tid & 63;
  for (int i = 0; i < 8; ++i) {
    int sl = wave * 8 + i;
    int s  = s0 + sl;
    float v[6]; float sum = 0.f, ss = 0.f;
    #pragma unroll
    for (int j = 0; j < 6; ++j) { v[j] = tile[sl][j * 64 + lane]; sum += v[j]; ss += v[j] * v[j]; }
    #pragma unroll
    for (int o = 32; o; o >>= 1) { sum += __shfl_xor(sum, o); ss += __shfl_xor(ss, o); }
    float mu   = sum * (1.f / 384.f);
    float var  = ss * (1.f / 384.f) - mu * mu;
    float rstd = rsqrtf(var + 1e-5f);
    int h = s / HW, wc = s - h * HW;
    int ir = h - 3;  if (ir < 0) ir += HW;
    int jr = wc - 3; if (jr < 0) jr += HW;
    int widx = img * 64 + (ir / WSZ) * 8 + (jr / WSZ);
    int tok  = (ir % WSZ) * WSZ + (jr % WSZ);
    size_t wrow = (size_t)(widx * NTOK + tok);
    float* xlr = xl + wrow * DIMC;          // residual in window order
    short* wr  = win + wrow * DIMC;
    #pragma unroll
    for (int j = 0; j < 6; ++j) {
      int c = j * 64 + lane;
      xlr[c] = v[j];
      wr[c]  = f2bf((v[j] - mu) * rstd * w[c] + b[c]);
    }
  }
}

// ---------------- GEMM core: 128x128 tile, BK=64, 4 waves, 16x16x32 bf16 MFMA ----------------
__device__ __forceinline__ void gemm_core(const short* __restrict__ A, int lda,
                                          const short* __restrict__ Bt, int ldb, int K,
                                          int m0, int n0, short* sA, short* sB,
                                          f32x4 acc[4][4]) {
  const int tid = threadIdx.x;
  const int wave = tid >> 6, lane = tid & 63;
  const int wm = (wave >> 1) << 6, wn = (wave & 1) << 6;
  const int lr = lane & 15, lk = lane >> 4;
  #pragma unroll
  for (int i = 0; i < 4; ++i)
    #pragma unroll
    for (int j = 0; j < 4; ++j)
      #pragma unroll
      for (int q = 0; q < 4; ++q) acc[i][j][q] = 0.f;

  for (int kt = 0; kt < K; kt += 64) {
    #pragma unroll
    for (int r = 0; r < 4; ++r) {
      int flat = r * 256 + tid;
      int row  = flat >> 3;
      int pcol = flat & 7;
      int lcol = pcol ^ (row & 7);            // inverse-swizzled global source
      async16(A  + (size_t)(m0 + row) * lda + kt + lcol * 8, sA + flat * 8);
      async16(Bt + (size_t)(n0 + row) * ldb + kt + lcol * 8, sB + flat * 8);
    }
    __syncthreads();
    #pragma unroll
    for (int kk = 0; kk < 2; ++kk) {
      short8 a[4], bfr[4];
      #pragma unroll
      for (int i = 0; i < 4; ++i) {
        int ra = wm + i * 16 + lr;
        int sa_ = (kk * 4 + lk) ^ (ra & 7);   // swizzled read
        a[i] = *(const short8*)(sA + ra * 64 + sa_ * 8);
        int rb = wn + i * 16 + lr;
        int sb_ = (kk * 4 + lk) ^ (rb & 7);
        bfr[i] = *(const short8*)(sB + rb * 64 + sb_ * 8);
      }
      #pragma unroll
      for (int i = 0; i < 4; ++i)
        #pragma unroll
        for (int j = 0; j < 4; ++j)
          acc[i][j] = __builtin_amdgcn_mfma_f32_16x16x32_bf16(a[i], bfr[j], acc[i][j], 0, 0, 0);
    }
    __syncthreads();
  }
}

// D-frag mapping (m89-verified): col = lane&15, row = (lane>>4)*4 + reg
#define EPI_PROLOGUE \
  const int tid = threadIdx.x; const int wave = tid >> 6, lane = tid & 63; \
  const int wm = (wave >> 1) << 6, wn = (wave & 1) << 6; \
  const int lr = lane & 15, lk = lane >> 4;

// ---------------- qkv GEMM: plain row-major [M][1152] output (mt-major order) ----------------
__global__ __launch_bounds__(256) void gemm_qkv(const short* __restrict__ A, const short* __restrict__ Bt,
                                                const float* __restrict__ bias, short* __restrict__ qkvr) {
  __shared__ __align__(16) short sA[8192], sB[8192];
  int mt = blockIdx.x / 9, nt = blockIdx.x - mt * 9;   // mt-major: 9 consecutive blocks share A-tile
  int m0 = mt << 7, n0 = nt << 7;
  f32x4 acc[4][4];
  gemm_core(A, 384, Bt, 384, 384, m0, n0, sA, sB, acc);
  EPI_PROLOGUE
  #pragma unroll
  for (int i = 0; i < 4; ++i)
    #pragma unroll
    for (int j = 0; j < 4; ++j)
      #pragma unroll
      for (int rg = 0; rg < 4; ++rg) {
        int row = m0 + wm + i * 16 + lk * 4 + rg;
        int col = n0 + wn + j * 16 + lr;
        qkvr[(size_t)row * QKVN + col] = f2bf(acc[i][j][rg] + bias[col]);
      }
}

// ---------------- MFMA attention: one block per (window,head); gathers from row-major qkv ----------------
#define QSTR 40   // Q/K/Vr LDS row stride (shorts): 80B, 16B-aligned
#define VSTR 72   // Vt/E LDS row stride (shorts): 144B, 16B-aligned
__global__ __launch_bounds__(256) void attn_kernel(const short* __restrict__ qkvr,
                                                   short* __restrict__ attn_out) {
  __shared__ __align__(16) short sQ[64 * QSTR];   // rows 49..63 stale: isolated to discarded D rows
  __shared__ __align__(16) short sK[64 * QSTR];   // rows 49..63 stale: masked before max
  __shared__ __align__(16) short sVr[NTOK * QSTR];// V row-major temp
  __shared__ __align__(16) short sVt[32 * VSTR];  // [d][tok]; cols 49..63 zeroed
  __shared__ __align__(16) short sE[64 * VSTR];   // unnormalized exp, bf16
  int bx = blockIdx.x;                       // widx*12 + hd
  int widx = bx / 12, hd = bx - widx * 12;
  int tid = threadIdx.x;
  const int w = tid >> 6, lane = tid & 63;
  const int lr = lane & 15, lk = lane >> 4;
  const short* base = qkvr + (size_t)widx * NTOK * QKVN + hd * HDIM;
  for (int i = tid; i < 196; i += 256) {     // 49 rows x 4 chunks of 16B
    int tok = i >> 2, p = (i & 3) << 3;
    const short* rp = base + (size_t)tok * QKVN + p;
    *(short8*)(sQ  + tok * QSTR + p) = *(const short8*)(rp);
    *(short8*)(sK  + tok * QSTR + p) = *(const short8*)(rp + 384);
    *(short8*)(sVr + tok * QSTR + p) = *(const short8*)(rp + 768);
  }
  __syncthreads();
  for (int e = tid; e < 2048; e += 256) {    // V transpose + pad-zero: sVt[d][tok]
    int d = e >> 6, c = e & 63;
    sVt[d * VSTR + c] = (c < NTOK) ? sVr[c * QSTR + d] : (short)0;
  }
  // ---- QK^T ----
  short8 aq = *(const short8*)(sQ + (16 * w + lr) * QSTR + lk * 8);
  f32x4 zero = {0.f, 0.f, 0.f, 0.f};
  f32x4 s4[4];
  #pragma unroll
  for (int j = 0; j < 4; ++j) {
    short8 bk = *(const short8*)(sK + (16 * j + lr) * QSTR + lk * 8);
    s4[j] = __builtin_amdgcn_mfma_f32_16x16x32_bf16(aq, bk, zero, 0, 0, 0);
  }
  // ---- softmax (rows (lane>>4)*4+rg of tile w; cols 16j+lr) ----
  float rinv[4];
  #pragma unroll
  for (int rg = 0; rg < 4; ++rg) {
    float v[4];
    #pragma unroll
    for (int j = 0; j < 4; ++j)
      v[j] = (16 * j + lr < NTOK) ? s4[j][rg] * 0.17677669529663687f : -3.0e38f;
    float m = fmaxf(fmaxf(v[0], v[1]), fmaxf(v[2], v[3]));
    #pragma unroll
    for (int o = 1; o < 16; o <<= 1) m = fmaxf(m, __shfl_xor(m, o));
    float e0 = __expf(v[0] - m), e1 = __expf(v[1] - m);
    float e2 = __expf(v[2] - m), e3 = __expf(v[3] - m);
    float sum = (e0 + e1) + (e2 + e3);
    #pragma unroll
    for (int o = 1; o < 16; o <<= 1) sum += __shfl_xor(sum, o);
    rinv[rg] = 1.f / sum;
    int erow = 16 * w + lk * 4 + rg;
    sE[erow * VSTR + lr]      = f2bf(e0);
    sE[erow * VSTR + 16 + lr] = f2bf(e1);
    sE[erow * VSTR + 32 + lr] = f2bf(e2);
    sE[erow * VSTR + 48 + lr] = f2bf(e3);
  }
  __syncthreads();                           // orders V-transpose + E writes before PV
  // ---- PV ----
  f32x4 o4[2] = {{0.f,0.f,0.f,0.f},{0.f,0.f,0.f,0.f}};
  #pragma unroll
  for (int ks = 0; ks < 2; ++ks) {
    short8 ae = *(const short8*)(sE + (16 * w + lr) * VSTR + ks * 32 + lk * 8);
    #pragma unroll
    for (int dt = 0; dt < 2; ++dt) {
      short8 bv = *(const short8*)(sVt + (16 * dt + lr) * VSTR + ks * 32 + lk * 8);
      o4[dt] = __builtin_amdgcn_mfma_f32_16x16x32_bf16(ae, bv, o4[dt], 0, 0, 0);
    }
  }
  #pragma unroll
  for (int rg = 0; rg < 4; ++rg) {
    int row = 16 * w + lk * 4 + rg;
    if (row < NTOK) {
      size_t rowbase = ((size_t)widx * NTOK + row) * DIMC + hd * HDIM;
      attn_out[rowbase + lr]      = f2bf(o4[0][rg] * rinv[rg]);
      attn_out[rowbase + 16 + lr] = f2bf(o4[1][rg] * rinv[rg]);
    }
  }
}

// ---------------- proj GEMM + LINEAR residual add into xl (window order) ----------------
__global__ __launch_bounds__(256) void gemm_proj(const short* __restrict__ A, const short* __restrict__ Bt,
                                                 const float* __restrict__ bias, float* __restrict__ xl) {
  __shared__ __align__(16) short sA[8192], sB[8192];
  int mt = blockIdx.x / 3, nt = blockIdx.x - mt * 3;
  int m0 = mt << 7, n0 = nt << 7;
  f32x4 acc[4][4];
  gemm_core(A, 384, Bt, 384, 384, m0, n0, sA, sB, acc);
  EPI_PROLOGUE
  #pragma unroll
  for (int i = 0; i < 4; ++i)
    #pragma unroll
    for (int j = 0; j < 4; ++j)
      #pragma unroll
      for (int rg = 0; rg < 4; ++rg) {
        int row = m0 + wm + i * 16 + lk * 4 + rg;
        int col = n0 + wn + j * 16 + lr;
        float* p = xl + (size_t)row * DIMC + col;
        *p = *p + acc[i][j][rg] + bias[col];
      }
}

// ---------------- LN2: xl f32 (window order) -> h2 bf16 ----------------
__global__ __launch_bounds__(256) void ln2_kernel(const float* __restrict__ xl, const float* __restrict__ w,
                                                  const float* __restrict__ b, short* __restrict__ h2) {
  int t = blockIdx.x * 4 + (threadIdx.x >> 6);
  int lane = threadIdx.x & 63;
  const float* row = xl + (size_t)t * DIMC;
  float v[6]; float sum = 0.f, ss = 0.f;
  #pragma unroll
  for (int j = 0; j < 3; ++j) {
    float2 p2 = *(const float2*)(row + j * 128 + lane * 2);
    v[2 * j] = p2.x; v[2 * j + 1] = p2.y;
    sum += p2.x + p2.y; ss += p2.x * p2.x + p2.y * p2.y;
  }
  #pragma unroll
  for (int o = 32; o; o >>= 1) { sum += __shfl_xor(sum, o); ss += __shfl_xor(ss, o); }
  float mu = sum * (1.f / 384.f);
  float var = ss * (1.f / 384.f) - mu * mu;
  float rstd = rsqrtf(var + 1e-5f);
  short* orow = h2 + (size_t)t * DIMC;
  #pragma unroll
  for (int j = 0; j < 3; ++j) {
    int c = j * 128 + lane * 2;
    short2 o2;
    o2.x = f2bf((v[2 * j] - mu) * rstd * w[c] + b[c]);
    o2.y = f2bf((v[2 * j + 1] - mu) * rstd * w[c + 1] + b[c + 1]);
    *(short2*)(orow + c) = o2;
  }
}

// ---------------- fc1 GEMM + exact GELU -> h3half ----------------
__global__ __launch_bounds__(256) void gemm_fc1(const short* __restrict__ A, const short* __restrict__ Bt,
                                                const float* __restrict__ bias, short* __restrict__ h3,
                                                int mbase) {
  __shared__ __align__(16) short sA[8192], sB[8192];
  int mt = blockIdx.x / 12, nt = blockIdx.x - mt * 12;   // mt-major
  int m0 = mbase + (mt << 7), n0 = nt << 7;
  f32x4 acc[4][4];
  gemm_core(A, 384, Bt, 384, 384, m0, n0, sA, sB, acc);
  EPI_PROLOGUE
  #pragma unroll
  for (int i = 0; i < 4; ++i)
    #pragma unroll
    for (int j = 0; j < 4; ++j)
      #pragma unroll
      for (int rg = 0; rg < 4; ++rg) {
        int row = m0 + wm + i * 16 + lk * 4 + rg;
        int col = n0 + wn + j * 16 + lr;
        float v = acc[i][j][rg] + bias[col];
        float g = 0.5f * v * (1.f + erff(v * 0.70710678118654752f));
        h3[(size_t)(row - mbase) * HIDDEN + col] = f2bf(g);
      }
}

// ---------------- fc2 GEMM + residual -> y (window order, linear coalesced stores) ----------------
__global__ __launch_bounds__(256) void gemm_fc2(const short* __restrict__ A, const short* __restrict__ Bt,
                                                const float* __restrict__ bias, const float* __restrict__ xl,
                                                float* __restrict__ y, int mbase) {
  __shared__ __align__(16) short sA[8192], sB[8192];
  int mt = blockIdx.x / 3, nt = blockIdx.x - mt * 3;     // mt-major
  int m0l = mt << 7, n0 = nt << 7;
  f32x4 acc[4][4];
  gemm_core(A, HIDDEN, Bt, HIDDEN, HIDDEN, m0l, n0, sA, sB, acc);
  EPI_PROLOGUE
  #pragma unroll
  for (int i = 0; i < 4; ++i)
    #pragma unroll
    for (int j = 0; j < 4; ++j)
      #pragma unroll
      for (int rg = 0; rg < 4; ++rg) {
        int rowl = m0l + wm + i * 16 + lk * 4 + rg;          // local (half) row
        int col  = n0 + wn + j * 16 + lr;
        y[(size_t)rowl * DIMC + col] =
            acc[i][j][rg] + bias[col] + xl[(size_t)(mbase + rowl) * DIMC + col];
      }
}

// ---------------- unwin: y (window order f32) -> NCHW out, LDS tile, both sides coalesced ----------------
__global__ __launch_bounds__(256) void unwin_kernel(const float* __restrict__ y,
                                                    float* __restrict__ out, int mbase) {
  __shared__ float tile[32][385];
  int bid  = blockIdx.x;                   // 8 * 98 per half
  int img8 = bid / 98;                     // 0..7 within half
  int img  = (mbase / SPIMG) + img8;       // global image
  int s0   = (bid - img8 * 98) * 32;
  int tid  = threadIdx.x;
  int wave = tid >> 6, lane = tid & 63;
  // phase 1: gather window rows (coalesced in c) into tile[rl][c]
  for (int rl = wave; rl < 32; rl += 4) {
    int s = s0 + rl;
    int h = s / HW, w_ = s - h * HW;
    int ir = h - 3;  if (ir < 0) ir += HW;     // rolled coords (same mapping as ln1)
    int jr = w_ - 3; if (jr < 0) jr += HW;
    int widx = img * 64 + (ir / WSZ) * 8 + (jr / WSZ);
    int tok  = (ir % WSZ) * WSZ + (jr % WSZ);
    const float* yr = y + (size_t)(widx * NTOK + tok - mbase) * DIMC;
    #pragma unroll
    for (int j = 0; j < 6; ++j) tile[rl][j * 64 + lane] = yr[j * 64 + lane];
  }
  __syncthreads();
  // phase 2: write NCHW coalesced (mirror of ln1 read phase)
  float* op = out + (size_t)img * DIMC * SPIMG + s0;
  #pragma unroll 4
  for (int it = 0; it < 48; ++it) {
    int idx = it * 256 + tid;
    int s = idx & 31, c = idx >> 5;
    op[(size_t)c * SPIMG + s] = tile[s][c];
  }
}

// ---------------- workspace layout (bytes), total 246,546,432 ----------------
#define OFF_XL    0u                // 50176*384*4  = 77,070,336   f32 residual (window order)
#define OFF_WIN   77070336u         // 50176*384*2  = 38,535,168   bf16 LN1-out / attn_out / h2
#define OFF_QKV   115605504u        // region 127,401,984: qkv rows 115.6MB | h3half 77.07 + y_half 38.5
#define OFF_Y     192675840u        // OFF_QKV + 77,070,336 (y_half inside region; end 231,211,008)
#define OFF_QKVT  243007488u        // 1152*384*2
#define OFF_PROJT 243892224u        // 384*384*2
#define OFF_FC1T  244187136u        // 1536*384*2
#define OFF_FC2T  245366784u        // 384*1536*2   (end = 246,546,432)
#define WS_NEEDED 246546432u

extern "C" void kernel_launch(void* const* d_in, const int* in_sizes, int n_in,
                              void* d_out, int out_size, void* d_ws, size_t ws_size,
                              hipStream_t stream) {
  if (ws_size < (size_t)WS_NEEDED) return;   // graceful diagnostic fail (constant per-call)

  const float* x      = (const float*)d_in[0];
  const float* n1w    = (const float*)d_in[1];
  const float* n1b    = (const float*)d_in[2];
  const float* qkv_w  = (const float*)d_in[3];
  const float* qkv_b  = (const float*)d_in[4];
  const float* proj_w = (const float*)d_in[5];
  const float* proj_b = (const float*)d_in[6];
  const float* n2w    = (const float*)d_in[7];
  const float* n2b    = (const float*)d_in[8];
  const float* fc1_w  = (const float*)d_in[9];
  const float* fc1_b  = (const float*)d_in[10];
  const float* fc2_w  = (const float*)d_in[11];
  const float* fc2_b  = (const float*)d_in[12];
  float* out = (float*)d_out;

  char* ws = (char*)d_ws;
  float* xl    = (float*)(ws + OFF_XL);
  short* win   = (short*)(ws + OFF_WIN);    // LN1 token rows; reused: attn_out, then h2
  short* qkvr  = (short*)(ws + OFF_QKV);    // qkv row-major; reused: h3half
  short* h3    = (short*)(ws + OFF_QKV);    // alias (qkv dead by fc1 time)
  float* yhalf = (float*)(ws + OFF_Y);      // fc2 output, window order, per half
  short* qkvT  = (short*)(ws + OFF_QKVT);
  short* projT = (short*)(ws + OFF_PROJT);
  short* fc1T  = (short*)(ws + OFF_FC1T);
  short* fc2T  = (short*)(ws + OFF_FC2T);

  wt_all_kernel<<<(1769472 + 255) / 256, 256, 0, stream>>>(qkv_w, proj_w, fc1_w, fc2_w,
                                                           qkvT, projT, fc1T, fc2T);
  ln1_win_kernel<<<16 * 98, 256, 0, stream>>>(x, n1w, n1b, xl, win);
  gemm_qkv<<<392 * 9, 256, 0, stream>>>(win, qkvT, qkv_b, qkvr);
  attn_kernel<<<1024 * 12, 256, 0, stream>>>(qkvr, win);          // win := attn_out
  gemm_proj<<<392 * 3, 256, 0, stream>>>(win, projT, proj_b, xl);
  ln2_kernel<<<12544, 256, 0, stream>>>(xl, n2w, n2b, win);       // win := h2
  // MLP half A (images 0-7)
  gemm_fc1<<<196 * 12, 256, 0, stream>>>(win, fc1T, fc1_b, h3, 0);
  gemm_fc2<<<196 * 3,  256, 0, stream>>>(h3, fc2T, fc2_b, xl, yhalf, 0);
  unwin_kernel<<<8 * 98, 256, 0, stream>>>(yhalf, out, 0);
  // MLP half B (images 8-15)
  gemm_fc1<<<196 * 12, 256, 0, stream>>>(win, fc1T, fc1_b, h3, MHALF);
  gemm_fc2<<<196 * 3,  256, 0, stream>>>(h3, fc2T, fc2_b, xl, yhalf, MHALF);
  unwin_kernel<<<8 * 98, 256, 0, stream>>>(yhalf, out, MHALF);

  (void)in_sizes; (void)n_in; (void)out_size; (void)ws_size;
}